// Round 8
// baseline (10592.606 us; speedup 1.0000x reference)
//
#include <hip/hip_runtime.h>

typedef __attribute__((ext_vector_type(8))) short short8;
typedef __attribute__((ext_vector_type(4))) float float4v;
typedef unsigned short u16;
typedef unsigned int u32;
typedef unsigned long long u64;

#define MFMA(a,b,c) __builtin_amdgcn_mfma_f32_16x16x32_bf16((a),(b),(c),0,0,0)
#define BH 32768  // 64*512 elements per [batch=64][512] slab
#define RD 8      // ring depth

__device__ __forceinline__ float b2f(u16 s){
  union{u32 u; float f;} x; x.u = ((u32)s)<<16; return x.f;
}
__device__ __forceinline__ u16 f2b(float f){
  union{u32 u; float f;} x; x.f=f;
  u32 r = x.u + 0x7FFFu + ((x.u>>16)&1u);
  return (u16)(r>>16);
}
__device__ __forceinline__ short8 ld8(const float* p){
  short8 r;
  #pragma unroll
  for (int e = 0; e < 8; ++e) r[e] = (short)f2b(p[e]);
  return r;
}
// ---- agent-scope (device-coherent) access ----------------------------------
__device__ __forceinline__ u32 ald(const u32* p){
  return __hip_atomic_load((u32*)p, __ATOMIC_RELAXED, __HIP_MEMORY_SCOPE_AGENT);
}
__device__ __forceinline__ void ast(u32* p, u32 v){
  __hip_atomic_store(p, v, __ATOMIC_RELAXED, __HIP_MEMORY_SCOPE_AGENT);
}
__device__ __forceinline__ short8 ld16a(const u16* p){
  union { u64 d[2]; short8 s; } u;
  const u64* q = (const u64*)p;
  u.d[0] = __hip_atomic_load((u64*)q,     __ATOMIC_RELAXED, __HIP_MEMORY_SCOPE_AGENT);
  u.d[1] = __hip_atomic_load((u64*)(q+1), __ATOMIC_RELAXED, __HIP_MEMORY_SCOPE_AGENT);
  return u.s;
}
__device__ __forceinline__ float sigm(float x){ return 1.f/(1.f+__expf(-x)); }
__device__ __forceinline__ float tanh_f(float x){
  float a = __expf(-2.f*fabsf(x));
  float t = (1.f-a)/(1.f+a);
  return x>=0.f ? t : -t;
}
__device__ __forceinline__ float lrelu(float x){ return x>=0.f? x : 0.01f*x; }

// busy-poll one flag until >= target (skip if target <= 0); flags 4B-stride
__device__ __forceinline__ void pollge(const u32* flags, int idx, int target){
  if (target > 0){
    while ((int)ald(flags + idx) < target) { }
  }
}
// end-of-round publish: drain this wave's stores, join block, tid0 posts flag
__device__ __forceinline__ void publish(u32* flags, int tid, int bid, int v){
  asm volatile("s_waitcnt vmcnt(0)" ::: "memory");
  __syncthreads();
  if (tid == 0) ast(flags + bid, (u32)v);
}

// ============================================================================
// Persistent pipelined kernel. 88 blocks, 1028 rounds, point-to-point flags.
//   L0   blocks  0..31 : round it in [1,1024]  h0[t=it-1]  -> h0R[t&7]
//   L1   blocks 32..63 : round it in [2,1025]  h1[t=it-2]  -> h1R[t&7]
//   ENC  blocks 64..67 : round it in [0,1023]  emb[t=it]   -> embR[t&7]
//   FCA  blocks 68..83 : round it in [3,1026]  fc1 preact t=it-3 -> fcaR[t&7]
//   FCB  blocks 84..87 : round it in [4,1027]  LN+fc2 t=it-4 -> d_out
// Flags (4B stride): block b publishes it+1 after round it. Depth-8 rings ->
// slot-free checks are "consumer flag >= it-6" (acyclic, deadlock-free).
// A-operands are burst-preloaded into VGPRs (1 wave/SIMD -> 512-reg budget)
// so LLC latency is paid once per round, not per MFMA.
// ============================================================================
__global__ __launch_bounds__(256, 1) void persist_kernel(
    const float* __restrict__ x,
    const float* __restrict__ Wenc, const float* __restrict__ benc,
    const float* __restrict__ genc, const float* __restrict__ beenc,
    const float* __restrict__ Wih0, const float* __restrict__ Whh0,
    const float* __restrict__ bih0, const float* __restrict__ bhh0,
    const float* __restrict__ Wih1, const float* __restrict__ Whh1,
    const float* __restrict__ bih1, const float* __restrict__ bhh1,
    const float* __restrict__ Wfc1, const float* __restrict__ bfc1,
    const float* __restrict__ gfc, const float* __restrict__ befc,
    const float* __restrict__ Wfc2, const float* __restrict__ bfc2,
    u16* embR, u16* h0R, u16* h1R, u16* fcaR, float* statsR, u32* flags,
    float* __restrict__ outp)
{
  __shared__ float4v ex2[4][12][64];   // 48 KB: [srcwave][gate*4+mtile][lane]
  __shared__ float hc[64][17];
  __shared__ float eS[4][16][2];
  __shared__ float gL[512], beL[512], w0L[512], w1L[512];
  __shared__ float fstM[16], fstR[16];

  const int tid = threadIdx.x;
  const int lane = tid & 63;
  const int wv = tid >> 6;
  const int c16 = lane & 15, quad = lane >> 4;
  const int bid = (int)blockIdx.x;
  const int NIT = 1028;

  if (bid < 64){
    // ------------------------- GRU layer role -------------------------------
    const int layer = bid >> 5;
    const int sb = (bid & 31) * 16;
    const bool isH = wv < 2;            // waves 0,1: h-part; waves 2,3: x-part
    const int ko0 = (wv & 1) * 8;       // kstep offset within the 512 half
    const float* Wih = layer ? Wih1 : Wih0;
    const float* Whh = layer ? Whh1 : Whh0;
    const float* bih = layer ? bih1 : bih0;
    const float* bhh = layer ? bhh1 : bhh0;
    const float* Wsrc = isH ? Whh : Wih;
    const int colg = sb + c16;

    short8 Wq[3][8];                    // 96 VGPRs of weights
    #pragma unroll
    for (int g = 0; g < 3; ++g)
      #pragma unroll
      for (int k = 0; k < 8; ++k)
        Wq[g][k] = ld8(Wsrc + (size_t)(colg + g*512)*512 + (ko0 + k)*32 + quad*8);
    const float bir = bih[colg],       bhr = bhh[colg];
    const float biz = bih[colg+512],   bhz = bhh[colg+512];
    const float bin_ = bih[colg+1024], bhn = bhh[colg+1024];

    for (int i = tid; i < 64*17; i += 256) (&hc[0][0])[i] = 0.f;
    __syncthreads();

    for (int it = 0; it < NIT; ++it){
      const bool active = layer ? (it >= 2 && it <= 1025) : (it >= 1 && it <= 1024);
      if (active){
        const int t = it - 1 - layer;
        // ---- per-wave dataflow polls (each wave waits only for what it uses)
        if (layer == 0){
          if (isH){
            if (lane < 32) pollge(flags, lane, it);           // L0 peers: h0[t-1]
            else           pollge(flags, lane, it - 6);       // L1 done with h0[t-8]
          } else {
            if (lane < 4)  pollge(flags, 64 + lane, it);      // ENC: emb[t]
          }
        } else {
          if (isH){
            if (lane < 32)      pollge(flags, 32 + lane, it);         // L1 peers: h1[t-1]
            else if (lane < 48) pollge(flags, 68 + (lane-32), it - 6);// FCA done with h1[t-8]
          } else {
            if (lane < 32) pollge(flags, lane, it);           // L0: h0[t]
          }
        }
        const u16* xs = layer ? (h0R + (size_t)(t & 7)*BH) : (embR + (size_t)(t & 7)*BH);
        u16* hring = layer ? h1R : h0R;
        const u16* hs = hring + (size_t)((t + 7) & 7)*BH;
        u16* out = hring + (size_t)(t & 7)*BH;
        const u16* Ah = isH ? hs : xs;

        // ---- burst-preload ALL 32 A-frags (64 u64 loads in flight) ---------
        short8 abuf[32];
        #pragma unroll
        for (int mt = 0; mt < 4; ++mt){
          const u16* arow = Ah + (size_t)(mt*16 + c16)*512 + ko0*32 + quad*8;
          #pragma unroll
          for (int k = 0; k < 8; ++k)
            abuf[mt*8 + k] = ld16a(arow + k*32);
        }
        float4v acc[12];
        #pragma unroll
        for (int i = 0; i < 12; ++i) acc[i] = float4v{0,0,0,0};
        #pragma unroll
        for (int mt = 0; mt < 4; ++mt)
          #pragma unroll
          for (int k = 0; k < 8; ++k){
            short8 a = abuf[mt*8 + k];
            acc[0*4+mt] = MFMA(a, Wq[0][k], acc[0*4+mt]);
            acc[1*4+mt] = MFMA(a, Wq[1][k], acc[1*4+mt]);
            acc[2*4+mt] = MFMA(a, Wq[2][k], acc[2*4+mt]);
          }
        #pragma unroll
        for (int i = 0; i < 12; ++i) ex2[wv][i][lane] = acc[i];
        __syncthreads();
        // wave w reduces + finishes M-tile w (rows 16w..16w+15)
        float4v R{0,0,0,0}, Z{0,0,0,0}, HN{0,0,0,0}, IN{0,0,0,0};
        #pragma unroll
        for (int src = 0; src < 4; ++src){
          R = R + ex2[src][0*4+wv][lane];
          Z = Z + ex2[src][1*4+wv][lane];
          float4v nn = ex2[src][2*4+wv][lane];
          if (src < 2) HN = HN + nn; else IN = IN + nn;
        }
        #pragma unroll
        for (int r = 0; r < 4; ++r){
          float rg = sigm(R[r] + bir + bhr);
          float zg = sigm(Z[r] + biz + bhz);
          float ng = tanh_f((IN[r] + bin_) + rg * (HN[r] + bhn));
          int m = wv*16 + quad*4 + r;
          float hold = hc[m][c16];
          float hnew = (1.f - zg)*ng + zg*hold;
          hc[m][c16] = hnew;
          u16 mine = f2b(hnew);
          u32 nb = (u32)(u16)__shfl_xor((int)mine, 1, 64);
          if (!(lane & 1))
            ast((u32*)(out + (size_t)m*512 + sb + c16), (u32)mine | (nb << 16));
        }
      }
      publish(flags, tid, bid, it + 1);
    }
  } else if (bid < 68){
    // ------------------------- ENC role (4 blocks x 16 rows) ---------------
    const int r0 = (bid - 64) * 16;
    const int wc0 = wv * 128;           // this wave's 128 columns
    short8 We[8][3];
    float eb[8], eg[8], ebe[8];
    #pragma unroll
    for (int tl = 0; tl < 8; ++tl){
      int col = wc0 + tl*16 + c16;
      #pragma unroll
      for (int kc = 0; kc < 3; ++kc)
        We[tl][kc] = ld8(Wenc + (size_t)col*96 + kc*32 + quad*8);
      eb[tl] = benc[col]; eg[tl] = genc[col]; ebe[tl] = beenc[col];
    }
    for (int it = 0; it < NIT; ++it){
      if (it <= 1023){
        const int t = it;
        if (lane < 32) pollge(flags, lane, it - 6);   // L0 done with emb[t-8]
        float4v ac[8];
        #pragma unroll
        for (int tl = 0; tl < 8; ++tl) ac[tl] = float4v{0,0,0,0};
        #pragma unroll
        for (int kc = 0; kc < 3; ++kc){
          short8 a = ld8(x + ((size_t)(r0 + c16)*1024 + t)*96 + kc*32 + quad*8);
          #pragma unroll
          for (int tl = 0; tl < 8; ++tl) ac[tl] = MFMA(a, We[tl][kc], ac[tl]);
        }
        float s[4] = {0,0,0,0}, q[4] = {0,0,0,0};
        #pragma unroll
        for (int tl = 0; tl < 8; ++tl)
          #pragma unroll
          for (int r = 0; r < 4; ++r){
            float v = lrelu(ac[tl][r] + eb[tl]);
            ac[tl][r] = v; s[r] += v; q[r] += v*v;
          }
        #pragma unroll
        for (int m = 1; m < 16; m <<= 1)
          #pragma unroll
          for (int r = 0; r < 4; ++r){ s[r] += __shfl_xor(s[r], m, 64); q[r] += __shfl_xor(q[r], m, 64); }
        if (c16 == 0){
          #pragma unroll
          for (int r = 0; r < 4; ++r){ eS[wv][quad*4+r][0] = s[r]; eS[wv][quad*4+r][1] = q[r]; }
        }
        __syncthreads();
        float mean[4], rstd[4];
        #pragma unroll
        for (int r = 0; r < 4; ++r){
          int rl = quad*4 + r;
          float ss = eS[0][rl][0]+eS[1][rl][0]+eS[2][rl][0]+eS[3][rl][0];
          float qq = eS[0][rl][1]+eS[1][rl][1]+eS[2][rl][1]+eS[3][rl][1];
          mean[r] = ss * (1.f/512.f);
          float var = qq * (1.f/512.f) - mean[r]*mean[r];
          rstd[r] = rsqrtf(var + 1e-5f);
        }
        u16* eo = embR + (size_t)(t & 7)*BH;
        #pragma unroll
        for (int tl = 0; tl < 8; ++tl)
          #pragma unroll
          for (int r = 0; r < 4; ++r){
            float o = (ac[tl][r] - mean[r]) * rstd[r] * eg[tl] + ebe[tl];
            u16 mine = f2b(o);
            u32 nb = (u32)(u16)__shfl_xor((int)mine, 1, 64);
            if (!(lane & 1))
              ast((u32*)(eo + (size_t)(r0 + quad*4 + r)*512 + wc0 + tl*16 + c16),
                  (u32)mine | (nb << 16));
          }
      }
      publish(flags, tid, bid, it + 1);
    }
  } else if (bid < 84){
    // ------------------------- FCA role (16 blocks x 32 cols) --------------
    const int f = bid - 68;
    const int fc0 = f * 32;
    short8 Wf[2][16];
    float fb1[2];
    #pragma unroll
    for (int tl = 0; tl < 2; ++tl){
      int col = fc0 + tl*16 + c16;
      #pragma unroll
      for (int k = 0; k < 16; ++k)
        Wf[tl][k] = ld8(Wfc1 + (size_t)col*512 + k*32 + quad*8);
      fb1[tl] = bfc1[col];
    }
    for (int it = 0; it < NIT; ++it){
      if (it >= 3 && it <= 1026){
        const int t = it - 3;
        if (lane < 32)      pollge(flags, 32 + lane, it);          // h1[t] ready
        else if (lane < 36) pollge(flags, 84 + (lane-32), it - 6); // FCB slot-free
        const u16* hrow = h1R + (size_t)(t & 7)*BH + (size_t)(wv*16 + c16)*512;
        short8 abuf[16];
        #pragma unroll
        for (int k = 0; k < 16; ++k) abuf[k] = ld16a(hrow + k*32 + quad*8);
        float4v a0{0,0,0,0}, a1{0,0,0,0};
        #pragma unroll
        for (int k = 0; k < 16; ++k){
          a0 = MFMA(abuf[k], Wf[0][k], a0);
          a1 = MFMA(abuf[k], Wf[1][k], a1);
        }
        u16* fo = fcaR + (size_t)(t & 7)*BH;
        float s[4], q[4];
        #pragma unroll
        for (int r = 0; r < 4; ++r){
          float v0 = lrelu(a0[r] + fb1[0]);
          float v1 = lrelu(a1[r] + fb1[1]);
          int row = wv*16 + quad*4 + r;
          u16 m0 = f2b(v0), m1 = f2b(v1);
          u32 n0 = (u32)(u16)__shfl_xor((int)m0, 1, 64);
          u32 n1 = (u32)(u16)__shfl_xor((int)m1, 1, 64);
          if (!(lane & 1)){
            ast((u32*)(fo + (size_t)row*512 + fc0      + c16), (u32)m0 | (n0 << 16));
            ast((u32*)(fo + (size_t)row*512 + fc0 + 16 + c16), (u32)m1 | (n1 << 16));
          }
          s[r] = v0 + v1; q[r] = v0*v0 + v1*v1;
        }
        #pragma unroll
        for (int m = 1; m < 16; m <<= 1)
          #pragma unroll
          for (int r = 0; r < 4; ++r){ s[r] += __shfl_xor(s[r], m, 64); q[r] += __shfl_xor(q[r], m, 64); }
        if (c16 == 0){
          #pragma unroll
          for (int r = 0; r < 4; ++r){
            int row = wv*16 + quad*4 + r;
            union{float f; u32 u;} sa, qa; sa.f = s[r]; qa.f = q[r];
            u32* sp = (u32*)&statsR[(((size_t)(t & 7)*16 + f)*64 + row)*2];
            ast(sp, sa.u); ast(sp + 1, qa.u);
          }
        }
      }
      publish(flags, tid, bid, it + 1);
    }
  } else {
    // ------------------------- FCB role (4 blocks x 16 rows) ---------------
    const int g0 = (bid - 84) * 16;
    for (int i = tid; i < 512; i += 256){
      gL[i]  = gfc[i];  beL[i] = befc[i];
      w0L[i] = Wfc2[i]; w1L[i] = Wfc2[512 + i];
    }
    const float f0 = bfc2[0], f1 = bfc2[1];
    __syncthreads();
    const int l16 = lane & 15, q16 = lane >> 4;
    for (int it = 0; it < NIT; ++it){
      if (it >= 4 && it <= 1027){
        const int t = it - 4;
        if (lane < 16) pollge(flags, 68 + lane, it);   // FCA done t
        const u16* fi = fcaR + (size_t)(t & 7)*BH;
        short8 pvb[4];
        #pragma unroll
        for (int rr = 0; rr < 4; ++rr)
          pvb[rr] = ld16a(fi + (size_t)(g0 + wv*4 + rr)*512 + lane*8);
        {
          int row = g0 + wv*4 + q16;
          const u32* sp = (const u32*)&statsR[(((size_t)(t & 7)*16 + l16)*64 + row)*2];
          union{u32 u; float f;} sa, qa; sa.u = ald(sp); qa.u = ald(sp + 1);
          float s = sa.f, q = qa.f;
          #pragma unroll
          for (int m = 1; m < 16; m <<= 1){ s += __shfl_xor(s, m, 64); q += __shfl_xor(q, m, 64); }
          if (l16 == 0){
            float mean = s * (1.f/512.f);
            float var = q * (1.f/512.f) - mean*mean;
            fstM[wv*4 + q16] = mean;
            fstR[wv*4 + q16] = rsqrtf(var + 1e-5f);
          }
        }
        __syncthreads();
        #pragma unroll
        for (int rr = 0; rr < 4; ++rr){
          int row = g0 + wv*4 + rr;
          float mean = fstM[wv*4 + rr], rstd = fstR[wv*4 + rr];
          short8 pv = pvb[rr];
          float p0 = 0.f, p1 = 0.f;
          #pragma unroll
          for (int e = 0; e < 8; ++e){
            int c = lane*8 + e;
            float v = (b2f((u16)pv[e]) - mean) * rstd * gL[c] + beL[c];
            p0 += v * w0L[c]; p1 += v * w1L[c];
          }
          #pragma unroll
          for (int m = 1; m < 64; m <<= 1){ p0 += __shfl_xor(p0, m, 64); p1 += __shfl_xor(p1, m, 64); }
          if (lane == 0){
            float2 ov; ov.x = p0 + f0; ov.y = p1 + f1;
            *(float2*)&outp[((size_t)row*1024 + t)*2] = ov;
          }
        }
        __syncthreads();
      }
      publish(flags, tid, bid, it + 1);
    }
  }
}

// ---------------- cls head on final hiddens ---------------------------------
__global__ __launch_bounds__(256) void cls_kernel(
    const u16* __restrict__ h0f, const u16* __restrict__ h1f,
    const float* __restrict__ W1, const float* __restrict__ b1,
    const float* __restrict__ gbn, const float* __restrict__ bebn,
    const float* __restrict__ W2, const float* __restrict__ b2,
    float* __restrict__ outc)
{
  __shared__ float hf[1024];
  __shared__ float cv[512];
  const int tid = threadIdx.x;
  const int b = blockIdx.x;
  for (int i = tid; i < 512; i += 256){
    hf[i] = b2f(h0f[(size_t)b*512 + i]);
    hf[512+i] = b2f(h1f[(size_t)b*512 + i]);
  }
  __syncthreads();
  const float bnscale = rsqrtf(1.f + 1e-5f);
  for (int j = tid; j < 512; j += 256){
    float a = 0.f;
    for (int c = 0; c < 256; ++c){
      float4v w = *(const float4v*)(W1 + (size_t)j*1024 + c*4);
      #pragma unroll
      for (int e = 0; e < 4; ++e) a += w[e] * hf[c*4 + e];
    }
    a = lrelu(a + b1[j]);
    cv[j] = a * bnscale * gbn[j] + bebn[j];
  }
  __syncthreads();
  const int wv = tid >> 6, lane = tid & 63;
  for (int o = wv; o < 9; o += 4){
    float p = 0.f;
    #pragma unroll
    for (int e = 0; e < 8; ++e) p += cv[lane*8 + e] * W2[(size_t)o*512 + lane*8 + e];
    #pragma unroll
    for (int m = 1; m < 64; m <<= 1) p += __shfl_xor(p, m, 64);
    if (lane == 0) outc[(size_t)b*9 + o] = p + b2[o];
  }
}

extern "C" void kernel_launch(void* const* d_in, const int* in_sizes, int n_in,
                              void* d_out, int out_size, void* d_ws, size_t ws_size,
                              hipStream_t stream)
{
  const float* x    = (const float*)d_in[0];
  const float* Wenc = (const float*)d_in[1];
  const float* benc = (const float*)d_in[2];
  const float* genc = (const float*)d_in[3];
  const float* beenc= (const float*)d_in[4];
  const float* Wih0 = (const float*)d_in[5];
  const float* Whh0 = (const float*)d_in[6];
  const float* bih0 = (const float*)d_in[7];
  const float* bhh0 = (const float*)d_in[8];
  const float* Wih1 = (const float*)d_in[9];
  const float* Whh1 = (const float*)d_in[10];
  const float* bih1 = (const float*)d_in[11];
  const float* bhh1 = (const float*)d_in[12];
  const float* Wfc1 = (const float*)d_in[13];
  const float* bfc1 = (const float*)d_in[14];
  const float* gfc  = (const float*)d_in[15];
  const float* befc = (const float*)d_in[16];
  const float* Wfc2 = (const float*)d_in[17];
  const float* bfc2 = (const float*)d_in[18];
  const float* Wcls1= (const float*)d_in[19];
  const float* bcls1= (const float*)d_in[20];
  const float* gbn  = (const float*)d_in[21];
  const float* bebn = (const float*)d_in[22];
  const float* Wcls2= (const float*)d_in[23];
  const float* bcls2= (const float*)d_in[24];
  (void)in_sizes; (void)n_in; (void)out_size; (void)ws_size;

  // ws layout (~2.1 MiB total):
  //   embR/h0R/h1R/fcaR: [8][64][512] u16 each (512 KiB each)
  //   statsR [8][16][64][2] f32 (64 KiB)   flags u32[128] (4B stride)
  u16* embR = (u16*)d_ws;
  u16* h0R  = embR + (size_t)RD*BH;
  u16* h1R  = h0R  + (size_t)RD*BH;
  u16* fcaR = h1R  + (size_t)RD*BH;
  float* statsR = (float*)(fcaR + (size_t)RD*BH);
  u32* flags = (u32*)(statsR + (size_t)RD*16*64*2);

  hipMemsetAsync(h0R, 0, (size_t)RD*BH*sizeof(u16), stream);
  hipMemsetAsync(h1R, 0, (size_t)RD*BH*sizeof(u16), stream);
  hipMemsetAsync(flags, 0, 512, stream);

  persist_kernel<<<88, 256, 0, stream>>>(
      x, Wenc, benc, genc, beenc,
      Wih0, Whh0, bih0, bhh0, Wih1, Whh1, bih1, bhh1,
      Wfc1, bfc1, gfc, befc, Wfc2, bfc2,
      embR, h0R, h1R, fcaR, statsR, flags, (float*)d_out);

  // final h0 = h0[1023] -> slot 1023&7 = 7; final h1 = h1[1023] -> slot 7
  cls_kernel<<<64, 256, 0, stream>>>(h0R + (size_t)7*BH, h1R + (size_t)7*BH,
                                     Wcls1, bcls1, gbn, bebn, Wcls2, bcls2,
                                     (float*)d_out + 131072);
}

// Round 9
// 7405.984 us; speedup vs baseline: 1.4303x; 1.4303x over previous
//
#include <hip/hip_runtime.h>

typedef __attribute__((ext_vector_type(8))) short short8;
typedef __attribute__((ext_vector_type(4))) float float4v;
typedef unsigned short u16;
typedef unsigned int u32;
typedef unsigned long long u64;

#define MFMA(a,b,c) __builtin_amdgcn_mfma_f32_16x16x32_bf16((a),(b),(c),0,0,0)
#define BH 32768  // 64*512 elements per [batch=64][512] slab
#define RD 8      // ring depth

__device__ __forceinline__ float b2f(u16 s){
  union{u32 u; float f;} x; x.u = ((u32)s)<<16; return x.f;
}
__device__ __forceinline__ u16 f2b(float f){
  union{u32 u; float f;} x; x.f=f;
  u32 r = x.u + 0x7FFFu + ((x.u>>16)&1u);
  return (u16)(r>>16);
}
__device__ __forceinline__ short8 ld8(const float* p){
  short8 r;
  #pragma unroll
  for (int e = 0; e < 8; ++e) r[e] = (short)f2b(p[e]);
  return r;
}
// ---- agent-scope (device-coherent) access ----------------------------------
__device__ __forceinline__ u32 ald(const u32* p){
  return __hip_atomic_load((u32*)p, __ATOMIC_RELAXED, __HIP_MEMORY_SCOPE_AGENT);
}
__device__ __forceinline__ void ast(u32* p, u32 v){
  __hip_atomic_store(p, v, __ATOMIC_RELAXED, __HIP_MEMORY_SCOPE_AGENT);
}
// coherent 16B load (bypass L1/L2, read fresh from LLC) as volatile asm:
// bursts of these issue back-to-back with all loads in flight.
__device__ __forceinline__ short8 ldx4cc(const u16* p){
  short8 v;
  asm volatile("global_load_dwordx4 %0, %1, off sc0 sc1"
               : "=v"(v) : "v"((u64)p) : "memory");
  return v;
}
__device__ __forceinline__ void waitvm0(){
  asm volatile("s_waitcnt vmcnt(0)" ::: "memory");
  __builtin_amdgcn_sched_barrier(0);   // MFMAs must not hoist above the wait
}
__device__ __forceinline__ float sigm(float x){ return 1.f/(1.f+__expf(-x)); }
__device__ __forceinline__ float tanh_f(float x){
  float a = __expf(-2.f*fabsf(x));
  float t = (1.f-a)/(1.f+a);
  return x>=0.f ? t : -t;
}
__device__ __forceinline__ float lrelu(float x){ return x>=0.f? x : 0.01f*x; }

// busy-poll one flag until >= target (skip if target <= 0); flags 4B-stride
__device__ __forceinline__ void pollge(const u32* flags, int idx, int target){
  if (target > 0){
    while ((int)ald(flags + idx) < target) { }
  }
}
// end-of-round publish: drain this wave's stores, join block, tid0 posts flag
__device__ __forceinline__ void publish(u32* flags, int tid, int bid, int v){
  asm volatile("s_waitcnt vmcnt(0)" ::: "memory");
  __syncthreads();
  if (tid == 0) ast(flags + bid, (u32)v);
}

// ============================================================================
// Persistent pipelined kernel. 88 blocks, 1028 rounds, point-to-point flags.
//   L0   blocks  0..31 : round it in [1,1024]  h0[t=it-1]  -> h0R[t&7]
//   L1   blocks 32..63 : round it in [2,1025]  h1[t=it-2]  -> h1R[t&7]
//   ENC  blocks 64..67 : round it in [0,1023]  emb[t=it]   -> embR[t&7]
//   FCA  blocks 68..83 : round it in [3,1026]  fc1 preact t=it-3 -> fcaR[t&7]
//   FCB  blocks 84..87 : round it in [4,1027]  LN+fc2 t=it-4 -> d_out
// Flags (4B stride): block b publishes it+1 after round it. Depth-8 rings ->
// slot-free checks are "consumer flag >= it-6" (acyclic, deadlock-free).
// A-operands are issued as one asm burst (all loads in flight, one waitcnt)
// so LLC latency is paid once per round, not once per 16B.
// ============================================================================
__global__ __launch_bounds__(256, 1) void persist_kernel(
    const float* __restrict__ x,
    const float* __restrict__ Wenc, const float* __restrict__ benc,
    const float* __restrict__ genc, const float* __restrict__ beenc,
    const float* __restrict__ Wih0, const float* __restrict__ Whh0,
    const float* __restrict__ bih0, const float* __restrict__ bhh0,
    const float* __restrict__ Wih1, const float* __restrict__ Whh1,
    const float* __restrict__ bih1, const float* __restrict__ bhh1,
    const float* __restrict__ Wfc1, const float* __restrict__ bfc1,
    const float* __restrict__ gfc, const float* __restrict__ befc,
    const float* __restrict__ Wfc2, const float* __restrict__ bfc2,
    u16* embR, u16* h0R, u16* h1R, u16* fcaR, float* statsR, u32* flags,
    float* __restrict__ outp)
{
  __shared__ float4v ex2[4][12][64];   // 48 KB: [srcwave][gate*4+mtile][lane]
  __shared__ float hc[64][17];
  __shared__ float eS[4][16][2];
  __shared__ float gL[512], beL[512], w0L[512], w1L[512];
  __shared__ float fstM[16], fstR[16];

  const int tid = threadIdx.x;
  const int lane = tid & 63;
  const int wv = tid >> 6;
  const int c16 = lane & 15, quad = lane >> 4;
  const int bid = (int)blockIdx.x;
  const int NIT = 1028;

  if (bid < 64){
    // ------------------------- GRU layer role -------------------------------
    const int layer = bid >> 5;
    const int sb = (bid & 31) * 16;
    const bool isH = wv < 2;            // waves 0,1: h-part; waves 2,3: x-part
    const int ko0 = (wv & 1) * 8;       // kstep offset within the 512 half
    const float* Wih = layer ? Wih1 : Wih0;
    const float* Whh = layer ? Whh1 : Whh0;
    const float* bih = layer ? bih1 : bih0;
    const float* bhh = layer ? bhh1 : bhh0;
    const float* Wsrc = isH ? Whh : Wih;
    const int colg = sb + c16;

    short8 Wq[3][8];                    // 96 VGPRs of weights
    #pragma unroll
    for (int g = 0; g < 3; ++g)
      #pragma unroll
      for (int k = 0; k < 8; ++k)
        Wq[g][k] = ld8(Wsrc + (size_t)(colg + g*512)*512 + (ko0 + k)*32 + quad*8);
    const float bir = bih[colg],       bhr = bhh[colg];
    const float biz = bih[colg+512],   bhz = bhh[colg+512];
    const float bin_ = bih[colg+1024], bhn = bhh[colg+1024];

    for (int i = tid; i < 64*17; i += 256) (&hc[0][0])[i] = 0.f;
    __syncthreads();

    for (int it = 0; it < NIT; ++it){
      const bool active = layer ? (it >= 2 && it <= 1025) : (it >= 1 && it <= 1024);
      if (active){
        const int t = it - 1 - layer;
        // ---- per-wave dataflow polls (each wave waits only for what it uses)
        if (layer == 0){
          if (isH){
            if (lane < 32) pollge(flags, lane, it);           // L0 peers: h0[t-1]
            else           pollge(flags, lane, it - 6);       // L1 done with h0[t-8]
          } else {
            if (lane < 4)  pollge(flags, 64 + lane, it);      // ENC: emb[t]
          }
        } else {
          if (isH){
            if (lane < 32)      pollge(flags, 32 + lane, it);         // L1 peers: h1[t-1]
            else if (lane < 48) pollge(flags, 68 + (lane-32), it - 6);// FCA done with h1[t-8]
          } else {
            if (lane < 32) pollge(flags, lane, it);           // L0: h0[t]
          }
        }
        const u16* xs = layer ? (h0R + (size_t)(t & 7)*BH) : (embR + (size_t)(t & 7)*BH);
        u16* hring = layer ? h1R : h0R;
        const u16* hs = hring + (size_t)((t + 7) & 7)*BH;
        u16* out = hring + (size_t)(t & 7)*BH;
        const u16* Ah = isH ? hs : xs;

        // ---- asm burst: all 32 coherent 16B loads in flight, one waitcnt ---
        short8 ab[32];
        #pragma unroll
        for (int mt = 0; mt < 4; ++mt){
          const u16* arow = Ah + (size_t)(mt*16 + c16)*512 + ko0*32 + quad*8;
          #pragma unroll
          for (int k = 0; k < 8; ++k)
            ab[mt*8 + k] = ldx4cc(arow + k*32);
        }
        waitvm0();
        float4v acc[12];
        #pragma unroll
        for (int i = 0; i < 12; ++i) acc[i] = float4v{0,0,0,0};
        #pragma unroll
        for (int mt = 0; mt < 4; ++mt)
          #pragma unroll
          for (int k = 0; k < 8; ++k){
            short8 a = ab[mt*8 + k];
            acc[0*4+mt] = MFMA(a, Wq[0][k], acc[0*4+mt]);
            acc[1*4+mt] = MFMA(a, Wq[1][k], acc[1*4+mt]);
            acc[2*4+mt] = MFMA(a, Wq[2][k], acc[2*4+mt]);
          }
        #pragma unroll
        for (int i = 0; i < 12; ++i) ex2[wv][i][lane] = acc[i];
        __syncthreads();
        // wave w reduces + finishes M-tile w (rows 16w..16w+15)
        float4v R{0,0,0,0}, Z{0,0,0,0}, HN{0,0,0,0}, IN{0,0,0,0};
        #pragma unroll
        for (int src = 0; src < 4; ++src){
          R = R + ex2[src][0*4+wv][lane];
          Z = Z + ex2[src][1*4+wv][lane];
          float4v nn = ex2[src][2*4+wv][lane];
          if (src < 2) HN = HN + nn; else IN = IN + nn;
        }
        #pragma unroll
        for (int r = 0; r < 4; ++r){
          float rg = sigm(R[r] + bir + bhr);
          float zg = sigm(Z[r] + biz + bhz);
          float ng = tanh_f((IN[r] + bin_) + rg * (HN[r] + bhn));
          int m = wv*16 + quad*4 + r;
          float hold = hc[m][c16];
          float hnew = (1.f - zg)*ng + zg*hold;
          hc[m][c16] = hnew;
          u16 mine = f2b(hnew);
          u32 nb = (u32)(u16)__shfl_xor((int)mine, 1, 64);
          if (!(lane & 1))
            ast((u32*)(out + (size_t)m*512 + sb + c16), (u32)mine | (nb << 16));
        }
      }
      publish(flags, tid, bid, it + 1);
    }
  } else if (bid < 68){
    // ------------------------- ENC role (4 blocks x 16 rows) ---------------
    const int r0 = (bid - 64) * 16;
    const int wc0 = wv * 128;           // this wave's 128 columns
    short8 We[8][3];
    float eb[8], eg[8], ebe[8];
    #pragma unroll
    for (int tl = 0; tl < 8; ++tl){
      int col = wc0 + tl*16 + c16;
      #pragma unroll
      for (int kc = 0; kc < 3; ++kc)
        We[tl][kc] = ld8(Wenc + (size_t)col*96 + kc*32 + quad*8);
      eb[tl] = benc[col]; eg[tl] = genc[col]; ebe[tl] = beenc[col];
    }
    for (int it = 0; it < NIT; ++it){
      if (it <= 1023){
        const int t = it;
        if (lane < 32) pollge(flags, lane, it - 6);   // L0 done with emb[t-8]
        float4v ac[8];
        #pragma unroll
        for (int tl = 0; tl < 8; ++tl) ac[tl] = float4v{0,0,0,0};
        #pragma unroll
        for (int kc = 0; kc < 3; ++kc){
          short8 a = ld8(x + ((size_t)(r0 + c16)*1024 + t)*96 + kc*32 + quad*8);
          #pragma unroll
          for (int tl = 0; tl < 8; ++tl) ac[tl] = MFMA(a, We[tl][kc], ac[tl]);
        }
        float s[4] = {0,0,0,0}, q[4] = {0,0,0,0};
        #pragma unroll
        for (int tl = 0; tl < 8; ++tl)
          #pragma unroll
          for (int r = 0; r < 4; ++r){
            float v = lrelu(ac[tl][r] + eb[tl]);
            ac[tl][r] = v; s[r] += v; q[r] += v*v;
          }
        #pragma unroll
        for (int m = 1; m < 16; m <<= 1)
          #pragma unroll
          for (int r = 0; r < 4; ++r){ s[r] += __shfl_xor(s[r], m, 64); q[r] += __shfl_xor(q[r], m, 64); }
        if (c16 == 0){
          #pragma unroll
          for (int r = 0; r < 4; ++r){ eS[wv][quad*4+r][0] = s[r]; eS[wv][quad*4+r][1] = q[r]; }
        }
        __syncthreads();
        float mean[4], rstd[4];
        #pragma unroll
        for (int r = 0; r < 4; ++r){
          int rl = quad*4 + r;
          float ss = eS[0][rl][0]+eS[1][rl][0]+eS[2][rl][0]+eS[3][rl][0];
          float qq = eS[0][rl][1]+eS[1][rl][1]+eS[2][rl][1]+eS[3][rl][1];
          mean[r] = ss * (1.f/512.f);
          float var = qq * (1.f/512.f) - mean[r]*mean[r];
          rstd[r] = rsqrtf(var + 1e-5f);
        }
        u16* eo = embR + (size_t)(t & 7)*BH;
        #pragma unroll
        for (int tl = 0; tl < 8; ++tl)
          #pragma unroll
          for (int r = 0; r < 4; ++r){
            float o = (ac[tl][r] - mean[r]) * rstd[r] * eg[tl] + ebe[tl];
            u16 mine = f2b(o);
            u32 nb = (u32)(u16)__shfl_xor((int)mine, 1, 64);
            if (!(lane & 1))
              ast((u32*)(eo + (size_t)(r0 + quad*4 + r)*512 + wc0 + tl*16 + c16),
                  (u32)mine | (nb << 16));
          }
      }
      publish(flags, tid, bid, it + 1);
    }
  } else if (bid < 84){
    // ------------------------- FCA role (16 blocks x 32 cols) --------------
    const int f = bid - 68;
    const int fc0 = f * 32;
    short8 Wf[2][16];
    float fb1[2];
    #pragma unroll
    for (int tl = 0; tl < 2; ++tl){
      int col = fc0 + tl*16 + c16;
      #pragma unroll
      for (int k = 0; k < 16; ++k)
        Wf[tl][k] = ld8(Wfc1 + (size_t)col*512 + k*32 + quad*8);
      fb1[tl] = bfc1[col];
    }
    for (int it = 0; it < NIT; ++it){
      if (it >= 3 && it <= 1026){
        const int t = it - 3;
        if (lane < 32)      pollge(flags, 32 + lane, it);          // h1[t] ready
        else if (lane < 36) pollge(flags, 84 + (lane-32), it - 6); // FCB slot-free
        const u16* hrow = h1R + (size_t)(t & 7)*BH + (size_t)(wv*16 + c16)*512;
        short8 ab[16];
        #pragma unroll
        for (int k = 0; k < 16; ++k) ab[k] = ldx4cc(hrow + k*32 + quad*8);
        waitvm0();
        float4v a0{0,0,0,0}, a1{0,0,0,0};
        #pragma unroll
        for (int k = 0; k < 16; ++k){
          a0 = MFMA(ab[k], Wf[0][k], a0);
          a1 = MFMA(ab[k], Wf[1][k], a1);
        }
        u16* fo = fcaR + (size_t)(t & 7)*BH;
        float s[4], q[4];
        #pragma unroll
        for (int r = 0; r < 4; ++r){
          float v0 = lrelu(a0[r] + fb1[0]);
          float v1 = lrelu(a1[r] + fb1[1]);
          int row = wv*16 + quad*4 + r;
          u16 m0 = f2b(v0), m1 = f2b(v1);
          u32 n0 = (u32)(u16)__shfl_xor((int)m0, 1, 64);
          u32 n1 = (u32)(u16)__shfl_xor((int)m1, 1, 64);
          if (!(lane & 1)){
            ast((u32*)(fo + (size_t)row*512 + fc0      + c16), (u32)m0 | (n0 << 16));
            ast((u32*)(fo + (size_t)row*512 + fc0 + 16 + c16), (u32)m1 | (n1 << 16));
          }
          s[r] = v0 + v1; q[r] = v0*v0 + v1*v1;
        }
        #pragma unroll
        for (int m = 1; m < 16; m <<= 1)
          #pragma unroll
          for (int r = 0; r < 4; ++r){ s[r] += __shfl_xor(s[r], m, 64); q[r] += __shfl_xor(q[r], m, 64); }
        if (c16 == 0){
          #pragma unroll
          for (int r = 0; r < 4; ++r){
            int row = wv*16 + quad*4 + r;
            union{float f; u32 u;} sa, qa; sa.f = s[r]; qa.f = q[r];
            u32* sp = (u32*)&statsR[(((size_t)(t & 7)*16 + f)*64 + row)*2];
            ast(sp, sa.u); ast(sp + 1, qa.u);
          }
        }
      }
      publish(flags, tid, bid, it + 1);
    }
  } else {
    // ------------------------- FCB role (4 blocks x 16 rows) ---------------
    const int g0 = (bid - 84) * 16;
    for (int i = tid; i < 512; i += 256){
      gL[i]  = gfc[i];  beL[i] = befc[i];
      w0L[i] = Wfc2[i]; w1L[i] = Wfc2[512 + i];
    }
    const float f0 = bfc2[0], f1 = bfc2[1];
    __syncthreads();
    const int l16 = lane & 15, q16 = lane >> 4;
    for (int it = 0; it < NIT; ++it){
      if (it >= 4 && it <= 1027){
        const int t = it - 4;
        if (lane < 16) pollge(flags, 68 + lane, it);   // FCA done t
        const u16* fi = fcaR + (size_t)(t & 7)*BH;
        short8 pvb[4];
        #pragma unroll
        for (int rr = 0; rr < 4; ++rr)
          pvb[rr] = ldx4cc(fi + (size_t)(g0 + wv*4 + rr)*512 + lane*8);
        {
          int row = g0 + wv*4 + q16;
          const u32* sp = (const u32*)&statsR[(((size_t)(t & 7)*16 + l16)*64 + row)*2];
          union{u32 u; float f;} sa, qa; sa.u = ald(sp); qa.u = ald(sp + 1);
          float s = sa.f, q = qa.f;
          #pragma unroll
          for (int m = 1; m < 16; m <<= 1){ s += __shfl_xor(s, m, 64); q += __shfl_xor(q, m, 64); }
          if (l16 == 0){
            float mean = s * (1.f/512.f);
            float var = q * (1.f/512.f) - mean*mean;
            fstM[wv*4 + q16] = mean;
            fstR[wv*4 + q16] = rsqrtf(var + 1e-5f);
          }
        }
        __syncthreads();
        waitvm0();
        #pragma unroll
        for (int rr = 0; rr < 4; ++rr){
          int row = g0 + wv*4 + rr;
          float mean = fstM[wv*4 + rr], rstd = fstR[wv*4 + rr];
          short8 pv = pvb[rr];
          float p0 = 0.f, p1 = 0.f;
          #pragma unroll
          for (int e = 0; e < 8; ++e){
            int c = lane*8 + e;
            float v = (b2f((u16)pv[e]) - mean) * rstd * gL[c] + beL[c];
            p0 += v * w0L[c]; p1 += v * w1L[c];
          }
          #pragma unroll
          for (int m = 1; m < 64; m <<= 1){ p0 += __shfl_xor(p0, m, 64); p1 += __shfl_xor(p1, m, 64); }
          if (lane == 0){
            float2 ov; ov.x = p0 + f0; ov.y = p1 + f1;
            *(float2*)&outp[((size_t)row*1024 + t)*2] = ov;
          }
        }
        __syncthreads();
      }
      publish(flags, tid, bid, it + 1);
    }
  }
}

// ---------------- cls head on final hiddens ---------------------------------
__global__ __launch_bounds__(256) void cls_kernel(
    const u16* __restrict__ h0f, const u16* __restrict__ h1f,
    const float* __restrict__ W1, const float* __restrict__ b1,
    const float* __restrict__ gbn, const float* __restrict__ bebn,
    const float* __restrict__ W2, const float* __restrict__ b2,
    float* __restrict__ outc)
{
  __shared__ float hf[1024];
  __shared__ float cv[512];
  const int tid = threadIdx.x;
  const int b = blockIdx.x;
  for (int i = tid; i < 512; i += 256){
    hf[i] = b2f(h0f[(size_t)b*512 + i]);
    hf[512+i] = b2f(h1f[(size_t)b*512 + i]);
  }
  __syncthreads();
  const float bnscale = rsqrtf(1.f + 1e-5f);
  for (int j = tid; j < 512; j += 256){
    float a = 0.f;
    for (int c = 0; c < 256; ++c){
      float4v w = *(const float4v*)(W1 + (size_t)j*1024 + c*4);
      #pragma unroll
      for (int e = 0; e < 4; ++e) a += w[e] * hf[c*4 + e];
    }
    a = lrelu(a + b1[j]);
    cv[j] = a * bnscale * gbn[j] + bebn[j];
  }
  __syncthreads();
  const int wv = tid >> 6, lane = tid & 63;
  for (int o = wv; o < 9; o += 4){
    float p = 0.f;
    #pragma unroll
    for (int e = 0; e < 8; ++e) p += cv[lane*8 + e] * W2[(size_t)o*512 + lane*8 + e];
    #pragma unroll
    for (int m = 1; m < 64; m <<= 1) p += __shfl_xor(p, m, 64);
    if (lane == 0) outc[(size_t)b*9 + o] = p + b2[o];
  }
}

extern "C" void kernel_launch(void* const* d_in, const int* in_sizes, int n_in,
                              void* d_out, int out_size, void* d_ws, size_t ws_size,
                              hipStream_t stream)
{
  const float* x    = (const float*)d_in[0];
  const float* Wenc = (const float*)d_in[1];
  const float* benc = (const float*)d_in[2];
  const float* genc = (const float*)d_in[3];
  const float* beenc= (const float*)d_in[4];
  const float* Wih0 = (const float*)d_in[5];
  const float* Whh0 = (const float*)d_in[6];
  const float* bih0 = (const float*)d_in[7];
  const float* bhh0 = (const float*)d_in[8];
  const float* Wih1 = (const float*)d_in[9];
  const float* Whh1 = (const float*)d_in[10];
  const float* bih1 = (const float*)d_in[11];
  const float* bhh1 = (const float*)d_in[12];
  const float* Wfc1 = (const float*)d_in[13];
  const float* bfc1 = (const float*)d_in[14];
  const float* gfc  = (const float*)d_in[15];
  const float* befc = (const float*)d_in[16];
  const float* Wfc2 = (const float*)d_in[17];
  const float* bfc2 = (const float*)d_in[18];
  const float* Wcls1= (const float*)d_in[19];
  const float* bcls1= (const float*)d_in[20];
  const float* gbn  = (const float*)d_in[21];
  const float* bebn = (const float*)d_in[22];
  const float* Wcls2= (const float*)d_in[23];
  const float* bcls2= (const float*)d_in[24];
  (void)in_sizes; (void)n_in; (void)out_size; (void)ws_size;

  // ws layout (~2.1 MiB total):
  //   embR/h0R/h1R/fcaR: [8][64][512] u16 each (512 KiB each)
  //   statsR [8][16][64][2] f32 (64 KiB)   flags u32[128] (4B stride)
  u16* embR = (u16*)d_ws;
  u16* h0R  = embR + (size_t)RD*BH;
  u16* h1R  = h0R  + (size_t)RD*BH;
  u16* fcaR = h1R  + (size_t)RD*BH;
  float* statsR = (float*)(fcaR + (size_t)RD*BH);
  u32* flags = (u32*)(statsR + (size_t)RD*16*64*2);

  hipMemsetAsync(h0R, 0, (size_t)RD*BH*sizeof(u16), stream);
  hipMemsetAsync(h1R, 0, (size_t)RD*BH*sizeof(u16), stream);
  hipMemsetAsync(flags, 0, 512, stream);

  persist_kernel<<<88, 256, 0, stream>>>(
      x, Wenc, benc, genc, beenc,
      Wih0, Whh0, bih0, bhh0, Wih1, Whh1, bih1, bhh1,
      Wfc1, bfc1, gfc, befc, Wfc2, bfc2,
      embR, h0R, h1R, fcaR, statsR, flags, (float*)d_out);

  // final h0 = h0[1023] -> slot 1023&7 = 7; final h1 = h1[1023] -> slot 7
  cls_kernel<<<64, 256, 0, stream>>>(h0R + (size_t)7*BH, h1R + (size_t)7*BH,
                                     Wcls1, bcls1, gbn, bebn, Wcls2, bcls2,
                                     (float*)d_out + 131072);
}